// Round 1
// baseline (5851.238 us; speedup 1.0000x reference)
//
#include <hip/hip_runtime.h>
#include <hip/hip_bf16.h>
#include <math.h>

// DecoderModel: B=2 S=2048 D=1024 V=32000, fp32 end-to-end (round 1 baseline).
// Structure: embed -> [attn1 -> add+LN] -> [attn2 -> add+LN] -> FF(relu, same W twice) -> vocab proj.
// NOTE: reference softmax is over axis=1 (the QUERY axis) with causal mask q>=k.

namespace {

constexpr int kB = 2;
constexpr int kS = 2048;
constexpr int kD = 1024;
constexpr int kV = 32000;
constexpr int kBS = kB * kS;               // 4096 rows
constexpr long kSD = (long)kS * kD;        // per-batch q/k/v stride
constexpr long kSS = (long)kS * kS;        // per-batch att stride
constexpr long kBSD = (long)kBS * kD;

constexpr int BM = 128, BN = 128, BK = 16;

#define LN_EPS 1e-5f

// ---------------------------------------------------------------- embed
__global__ __launch_bounds__(256)
void embed_k(const int* __restrict__ x, const float* __restrict__ emb,
             const float* __restrict__ pos, float* __restrict__ h0)
{
    const long bs = blockIdx.x;            // 0..B*S-1
    const int s = (int)(bs & (kS - 1));
    const int tok = x[bs];
    const int t = threadIdx.x;             // 256 threads * float4 = 1024 = D
    float4 e = reinterpret_cast<const float4*>(emb + (long)tok * kD)[t];
    const float4 p = reinterpret_cast<const float4*>(pos + (long)s * kD)[t];
    e.x += p.x; e.y += p.y; e.z += p.z; e.w += p.w;
    reinterpret_cast<float4*>(h0 + bs * kD)[t] = e;
}

// ---------------------------------------------------------------- GEMM
// C[M,N] = A[M,K] * B + bias.  BT=true: B is [N,K] row-major (use B^T, torch
// Linear weights / QK^T). BT=false: B is [K,N] row-major (PV).
// All of M%128, N%128, K%16 == 0 for every call site -> no guards.
template<bool BT, bool RELU, bool HAS_BIAS>
__global__ __launch_bounds__(256)
void gemm_f32(const float* __restrict__ A, const float* __restrict__ B,
              const float* __restrict__ bias, float* __restrict__ C,
              int M, int N, int K, long sA, long sB, long sC)
{
    A += (long)blockIdx.z * sA;
    B += (long)blockIdx.z * sB;
    C += (long)blockIdx.z * sC;

    __shared__ float As[BK][BM + 4];   // [k][m], padded
    __shared__ float Bs[BK][BN + 4];   // [k][n], padded

    const int tid = threadIdx.x;
    const int bm = blockIdx.y * BM;
    const int bn = blockIdx.x * BN;
    const int tm = (tid >> 4) << 3;    // 16x16 thread grid, 8x8 micro-tile
    const int tn = (tid & 15) << 3;

    float acc[8][8];
#pragma unroll
    for (int i = 0; i < 8; ++i)
#pragma unroll
        for (int j = 0; j < 8; ++j) acc[i][j] = 0.f;

    for (int kt = 0; kt < K; kt += BK) {
        // A tile: 128x16, transpose into As[k][m]
#pragma unroll
        for (int it = 0; it < 2; ++it) {
            const int f = tid + it * 256;
            const int r = f >> 2;
            const int c = (f & 3) << 2;
            const float4 a4 = *reinterpret_cast<const float4*>(&A[(long)(bm + r) * K + kt + c]);
            As[c + 0][r] = a4.x; As[c + 1][r] = a4.y; As[c + 2][r] = a4.z; As[c + 3][r] = a4.w;
        }
        if constexpr (BT) {
#pragma unroll
            for (int it = 0; it < 2; ++it) {
                const int f = tid + it * 256;
                const int r = f >> 2;
                const int c = (f & 3) << 2;
                const float4 b4 = *reinterpret_cast<const float4*>(&B[(long)(bn + r) * K + kt + c]);
                Bs[c + 0][r] = b4.x; Bs[c + 1][r] = b4.y; Bs[c + 2][r] = b4.z; Bs[c + 3][r] = b4.w;
            }
        } else {
#pragma unroll
            for (int it = 0; it < 2; ++it) {
                const int f = tid + it * 256;
                const int r = f >> 5;
                const int c = (f & 31) << 2;
                const float4 b4 = *reinterpret_cast<const float4*>(&B[(long)(kt + r) * N + bn + c]);
                *reinterpret_cast<float4*>(&Bs[r][c]) = b4;
            }
        }
        __syncthreads();

#pragma unroll
        for (int kk = 0; kk < BK; ++kk) {
            float a[8], b[8];
            *reinterpret_cast<float4*>(&a[0]) = *reinterpret_cast<const float4*>(&As[kk][tm]);
            *reinterpret_cast<float4*>(&a[4]) = *reinterpret_cast<const float4*>(&As[kk][tm + 4]);
            *reinterpret_cast<float4*>(&b[0]) = *reinterpret_cast<const float4*>(&Bs[kk][tn]);
            *reinterpret_cast<float4*>(&b[4]) = *reinterpret_cast<const float4*>(&Bs[kk][tn + 4]);
#pragma unroll
            for (int i = 0; i < 8; ++i)
#pragma unroll
                for (int j = 0; j < 8; ++j)
                    acc[i][j] = fmaf(a[i], b[j], acc[i][j]);
        }
        __syncthreads();
    }

    float bv[8];
    if constexpr (HAS_BIAS) {
        *reinterpret_cast<float4*>(&bv[0]) = *reinterpret_cast<const float4*>(&bias[bn + tn]);
        *reinterpret_cast<float4*>(&bv[4]) = *reinterpret_cast<const float4*>(&bias[bn + tn + 4]);
    }
#pragma unroll
    for (int i = 0; i < 8; ++i) {
        float o[8];
#pragma unroll
        for (int j = 0; j < 8; ++j) {
            float v = acc[i][j];
            if constexpr (HAS_BIAS) v += bv[j];
            if constexpr (RELU) v = fmaxf(v, 0.f);
            o[j] = v;
        }
        float* crow = C + (long)(bm + tm + i) * N + bn + tn;
        *reinterpret_cast<float4*>(crow) = *reinterpret_cast<const float4*>(&o[0]);
        *reinterpret_cast<float4*>(crow + 4) = *reinterpret_cast<const float4*>(&o[4]);
    }
}

// ---------------------------------------------------------------- column softmax
// softmax over the QUERY axis (axis=1): for each column k, normalize over
// q in [k, S). Masked entries (q<k) are written as exact 0 so PV is dense GEMM.
// Block: 256 threads = 32 columns x 8 q-stripes. Grid: (S/32, B).
__global__ __launch_bounds__(256)
void col_softmax(float* __restrict__ att)
{
    const int S = kS;
    const int kx = threadIdx.x & 31;
    const int qy = threadIdx.x >> 5;
    const int k = blockIdx.x * 32 + kx;
    float* base = att + (long)blockIdx.y * kSS;

    __shared__ float redm[8][33];
    __shared__ float reds[8][33];

    // first q >= k with q == qy (mod 8)
    const int q0 = k + ((qy - k) & 7);

    float m = -3.4e38f;
    for (int q = q0; q < S; q += 8)
        m = fmaxf(m, base[(long)q * S + k]);
    redm[qy][kx] = m;
    __syncthreads();
    if (qy == 0) {
#pragma unroll
        for (int r = 1; r < 8; ++r) m = fmaxf(m, redm[r][kx]);
        redm[0][kx] = m;
    }
    __syncthreads();
    m = redm[0][kx];

    float s = 0.f;
    for (int q = q0; q < S; q += 8)
        s += __expf(base[(long)q * S + k] - m);
    reds[qy][kx] = s;
    __syncthreads();
    if (qy == 0) {
#pragma unroll
        for (int r = 1; r < 8; ++r) s += reds[r][kx];
        reds[0][kx] = s;
    }
    __syncthreads();
    const float inv = 1.f / reds[0][kx];

    for (int q = qy; q < S; q += 8) {
        const long idx = (long)q * S + k;
        base[idx] = (q >= k) ? __expf(base[idx] - m) * inv : 0.f;
    }
}

// ---------------------------------------------------------------- add + LayerNorm
// One block per row; 256 threads x float4 = D=1024.
__global__ __launch_bounds__(256)
void add_ln(const float* __restrict__ X, const float* __restrict__ R,
            const float* __restrict__ g, const float* __restrict__ beta,
            float* __restrict__ Y)
{
    const long row = blockIdx.x;
    const int t = threadIdx.x;
    float4 v = reinterpret_cast<const float4*>(X + row * kD)[t];
    const float4 r = reinterpret_cast<const float4*>(R + row * kD)[t];
    v.x += r.x; v.y += r.y; v.z += r.z; v.w += r.w;

    float sum = v.x + v.y + v.z + v.w;
    float sq = v.x * v.x + v.y * v.y + v.z * v.z + v.w * v.w;
#pragma unroll
    for (int o = 32; o > 0; o >>= 1) {
        sum += __shfl_xor(sum, o);
        sq  += __shfl_xor(sq, o);
    }
    __shared__ float wsum[4], wsq[4];
    const int wave = t >> 6;
    if ((t & 63) == 0) { wsum[wave] = sum; wsq[wave] = sq; }
    __syncthreads();
    sum = wsum[0] + wsum[1] + wsum[2] + wsum[3];
    sq  = wsq[0] + wsq[1] + wsq[2] + wsq[3];
    const float mu = sum * (1.f / kD);
    const float var = sq * (1.f / kD) - mu * mu;
    const float rs = rsqrtf(var + LN_EPS);

    const float4 gv = reinterpret_cast<const float4*>(g)[t];
    const float4 bv = reinterpret_cast<const float4*>(beta)[t];
    float4 o;
    o.x = (v.x - mu) * rs * gv.x + bv.x;
    o.y = (v.y - mu) * rs * gv.y + bv.y;
    o.z = (v.z - mu) * rs * gv.z + bv.z;
    o.w = (v.w - mu) * rs * gv.w + bv.w;
    reinterpret_cast<float4*>(Y + row * kD)[t] = o;
}

} // namespace

// ---------------------------------------------------------------- launch
extern "C" void kernel_launch(void* const* d_in, const int* in_sizes, int n_in,
                              void* d_out, int out_size, void* d_ws, size_t ws_size,
                              hipStream_t stream)
{
    const int*   x   = (const int*)d_in[0];
    const float* emb = (const float*)d_in[1];
    const float* pos = (const float*)d_in[2];
    const float* k1w = (const float*)d_in[3];  const float* k1b = (const float*)d_in[4];
    const float* q1w = (const float*)d_in[5];  const float* q1b = (const float*)d_in[6];
    const float* v1w = (const float*)d_in[7];  const float* v1b = (const float*)d_in[8];
    const float* k2w = (const float*)d_in[9];  const float* k2b = (const float*)d_in[10];
    const float* q2w = (const float*)d_in[11]; const float* q2b = (const float*)d_in[12];
    const float* v2w = (const float*)d_in[13]; const float* v2b = (const float*)d_in[14];
    const float* lng = (const float*)d_in[15]; const float* lnb = (const float*)d_in[16];
    const float* ffw = (const float*)d_in[17]; const float* ffb = (const float*)d_in[18];
    const float* ow  = (const float*)d_in[19]; const float* ob  = (const float*)d_in[20];
    float* out = (float*)d_out;

    float* ws = (float*)d_ws;
    float* h0  = ws;
    float* wq  = ws + 1 * kBSD;
    float* wk  = ws + 2 * kBSD;
    float* wv  = ws + 3 * kBSD;
    float* ao  = ws + 4 * kBSD;
    float* h1  = ws + 5 * kBSD;
    float* h2  = ws + 6 * kBSD;
    float* att = ws + 7 * kBSD;   // B*S*S floats

    const dim3 blk(256);

    hipLaunchKernelGGL(embed_k, dim3(kBS), blk, 0, stream, x, emb, pos, h0);

    // h @ W^T + b over flattened [B*S, D]
    auto linNT = [&](const float* A, const float* W, const float* bias, float* C,
                     int N, bool relu) {
        const dim3 grid(N / BN, kBS / BM, 1);
        if (relu)
            hipLaunchKernelGGL((gemm_f32<true, true, true>), grid, blk, 0, stream,
                               A, W, bias, C, kBS, N, kD, 0L, 0L, 0L);
        else
            hipLaunchKernelGGL((gemm_f32<true, false, true>), grid, blk, 0, stream,
                               A, W, bias, C, kBS, N, kD, 0L, 0L, 0L);
    };

    auto attention = [&](const float* h,
                         const float* kw_, const float* kb_,
                         const float* qw_, const float* qb_,
                         const float* vw_, const float* vb_) {
        linNT(h, qw_, qb_, wq, kD, false);
        linNT(h, kw_, kb_, wk, kD, false);
        linNT(h, vw_, vb_, wv, kD, false);
        // att[b,q,k] = sum_d q[q,d] k[k,d]  (batched, NT)
        hipLaunchKernelGGL((gemm_f32<true, false, false>), dim3(kS / BN, kS / BM, kB), blk, 0, stream,
                           wq, wk, nullptr, att, kS, kS, kD, kSD, kSD, kSS);
        hipLaunchKernelGGL(col_softmax, dim3(kS / 32, kB), blk, 0, stream, att);
        // ao[b,q,d] = sum_k att[q,k] v[k,d]  (batched, NN)
        hipLaunchKernelGGL((gemm_f32<false, false, false>), dim3(kD / BN, kS / BM, kB), blk, 0, stream,
                           att, wv, nullptr, ao, kS, kD, kS, kSS, kSD, kSD);
    };

    // layer 1
    attention(h0, k1w, k1b, q1w, q1b, v1w, v1b);
    hipLaunchKernelGGL(add_ln, dim3(kBS), blk, 0, stream, ao, h0, lng, lnb, h1);
    // layer 2
    attention(h1, k2w, k2b, q2w, q2b, v2w, v2b);
    hipLaunchKernelGGL(add_ln, dim3(kBS), blk, 0, stream, ao, h1, lng, lnb, h2);

    // FF: same linear twice with relu between; reuse wq/wk as f1/f2
    linNT(h2, ffw, ffb, wq, kD, true);
    linNT(wq, ffw, ffb, wk, kD, false);

    // vocab projection -> d_out
    hipLaunchKernelGGL((gemm_f32<true, false, true>), dim3(kV / BN, kBS / BM, 1), blk, 0, stream,
                       wk, ow, ob, out, kBS, kV, kD, 0L, 0L, 0L);
}

// Round 5
// 1876.458 us; speedup vs baseline: 3.1182x; 3.1182x over previous
//
#include <hip/hip_runtime.h>
#include <hip/hip_bf16.h>
#include <math.h>

// DecoderModel B=2 S=2048 D=1024 V=32000 — round 3 kernel (2nd resubmit; rounds 3/4
// both failed with infra GPUAcquisitionTimeout, kernel never ran).
// bf16 MFMA everywhere; the Q/K->logits chain uses SPLIT bf16 (hi+lo, 3 MFMA
// passes) for fp32-equivalent precision, since round 2 showed plain-bf16 QK
// drives absmax to 0.05 (>0.019 gate). fp32 softmax/LN/residual.
//
// GEMM forms (all NT, both operands K-contiguous):
//   Linear:  C[bs,n] = h[bs,:] . W[n,:]      (col bias)
//   V^T:     vt[d,s] = Wv[d,:] . h[s,:]      (row bias)
//   QK^T:    att[q,k] = q[q,:] . k[k,:]      (split x split -> fp32)
//   PV:      ao[q,d]  = att[q,:] . vt[d,:]
// Softmax over QUERY axis (reference dim=1), causal q>=k, masked -> 0.

namespace {

typedef unsigned short u16;
typedef __bf16 bf16x8 __attribute__((ext_vector_type(8)));
typedef float f32x4 __attribute__((ext_vector_type(4)));
typedef u16 u16x4 __attribute__((ext_vector_type(4)));

constexpr int kB = 2, kS = 2048, kD = 1024, kV = 32000;
constexpr int kBS = kB * kS;                 // 4096
constexpr long kSD = (long)kS * kD;          // 2,097,152
constexpr long kSS = (long)kS * kS;          // 4,194,304
constexpr long kDD = (long)kD * kD;          // 1,048,576
constexpr long kBSD = (long)kBS * kD;        // 4,194,304

#define LN_EPS 1e-5f

__device__ __forceinline__ u16 f2bf(float f) {
    union { float f; unsigned u; } v; v.f = f;
    unsigned r = v.u + 0x7FFFu + ((v.u >> 16) & 1u);   // RNE
    return (u16)(r >> 16);
}
__device__ __forceinline__ float bf2f(u16 h) {
    union { unsigned u; float f; } v; v.u = ((unsigned)h) << 16; return v.f;
}

__device__ __forceinline__ void gload16(const void* g, void* l) {
    __builtin_amdgcn_global_load_lds(
        (const __attribute__((address_space(1))) unsigned int*)g,
        (__attribute__((address_space(3))) unsigned int*)l, 16, 0, 0);
}

// ------------------------------------------------------------------ embed (+split bf16)
__global__ __launch_bounds__(256)
void embed_k(const int* __restrict__ x, const float* __restrict__ emb,
             const float* __restrict__ pos, float* __restrict__ h0,
             u16* __restrict__ hHi, u16* __restrict__ hLo)
{
    const long bs = blockIdx.x;
    const int s = (int)(bs & (kS - 1));
    const int tok = x[bs];
    const int t = threadIdx.x;
    float4 e = reinterpret_cast<const float4*>(emb + (long)tok * kD)[t];
    const float4 p = reinterpret_cast<const float4*>(pos + (long)s * kD)[t];
    e.x += p.x; e.y += p.y; e.z += p.z; e.w += p.w;
    reinterpret_cast<float4*>(h0 + bs * kD)[t] = e;
    u16x4 hi = { f2bf(e.x), f2bf(e.y), f2bf(e.z), f2bf(e.w) };
    u16x4 lo = { f2bf(e.x - bf2f(hi.x)), f2bf(e.y - bf2f(hi.y)),
                 f2bf(e.z - bf2f(hi.z)), f2bf(e.w - bf2f(hi.w)) };
    reinterpret_cast<u16x4*>(hHi + bs * kD)[t] = hi;
    reinterpret_cast<u16x4*>(hLo + bs * kD)[t] = lo;
}

// ------------------------------------------------------------------ weight converts
// hi planes 0..6 (k1,q1,v1,k2,q2,v2,ff); lo planes for k1->7, q1->8, k2->9, q2->10.
struct W7 { const float* p[7]; };

__global__ __launch_bounds__(256)
void cvt7s(W7 w, u16* __restrict__ out)   // grid (kDD/1024, 7)
{
    const int wsel = blockIdx.y;
    const int loIdx7[7] = {7, 8, -1, 9, 10, -1, -1};
    const float* __restrict__ src = w.p[wsel];
    const long i = (long)blockIdx.x * 256 + threadIdx.x;
    const float4 v = reinterpret_cast<const float4*>(src)[i];
    u16x4 hi = { f2bf(v.x), f2bf(v.y), f2bf(v.z), f2bf(v.w) };
    reinterpret_cast<u16x4*>(out + (long)wsel * kDD)[i] = hi;
    const int li = loIdx7[wsel];
    if (li >= 0) {
        u16x4 lo = { f2bf(v.x - bf2f(hi.x)), f2bf(v.y - bf2f(hi.y)),
                     f2bf(v.z - bf2f(hi.z)), f2bf(v.w - bf2f(hi.w)) };
        reinterpret_cast<u16x4*>(out + (long)li * kDD)[i] = lo;
    }
}

__global__ __launch_bounds__(256)
void cvt_big(const float* __restrict__ src, u16* __restrict__ dst, long n4)
{
    for (long i = (long)blockIdx.x * 256 + threadIdx.x; i < n4; i += (long)gridDim.x * 256) {
        const float4 v = reinterpret_cast<const float4*>(src)[i];
        u16x4 o = { f2bf(v.x), f2bf(v.y), f2bf(v.z), f2bf(v.w) };
        reinterpret_cast<u16x4*>(dst)[i] = o;
    }
}

// ------------------------------------------------------------------ plain bf16 GEMM (NT)
// C[M,N] = A[M,K].B[N,K]^T (+bias). 128x128 tile, BK=32, 4 waves of 64x64.
// BIAS_MODE: 0 none, 1 bias[col], 2 bias[row].
template<int BIAS_MODE, bool RELU, bool OUT_BF16>
__global__ __launch_bounds__(256)
void gemm_bf16(const u16* __restrict__ A, const u16* __restrict__ B,
               const float* __restrict__ bias, void* __restrict__ Cv,
               int N, int K, long sA, long sB, long sC)
{
    __shared__ __bf16 As[128][32];
    __shared__ __bf16 Bs[128][32];

    const u16* Ab = A + (long)blockIdx.z * sA;
    const u16* Bb = B + (long)blockIdx.z * sB;

    const int tid = threadIdx.x;
    const int lane = tid & 63;
    const int wid = tid >> 6;
    const int wr = wid >> 1, wc = wid & 1;
    const int fr = lane & 15, fq = lane >> 4;
    const int bm = blockIdx.y * 128;
    const int bn = blockIdx.x * 128;

    const int c0 = wid * 2;
    const int srow = lane >> 2;
    const int skof = (lane & 3) * 8;
    const u16* gA = Ab + (size_t)(bm + c0 * 16 + srow) * K + skof;
    const u16* gB = Bb + (size_t)(bn + c0 * 16 + srow) * K + skof;

    f32x4 acc[4][4];
#pragma unroll
    for (int i = 0; i < 4; ++i)
#pragma unroll
        for (int j = 0; j < 4; ++j) acc[i][j] = (f32x4){0.f, 0.f, 0.f, 0.f};

    auto stage = [&](int kt) {
        gload16(gA + kt,                  &As[c0 * 16][0]);
        gload16(gA + kt + (size_t)16 * K, &As[c0 * 16 + 16][0]);
        gload16(gB + kt,                  &Bs[c0 * 16][0]);
        gload16(gB + kt + (size_t)16 * K, &Bs[c0 * 16 + 16][0]);
    };

    stage(0);
    for (int kt = 0;;) {
        __syncthreads();
        bf16x8 af[4], bfv[4];
#pragma unroll
        for (int i = 0; i < 4; ++i)
            af[i] = *reinterpret_cast<const bf16x8*>(&As[wr * 64 + i * 16 + fr][fq * 8]);
#pragma unroll
        for (int j = 0; j < 4; ++j)
            bfv[j] = *reinterpret_cast<const bf16x8*>(&Bs[wc * 64 + j * 16 + fr][fq * 8]);
#pragma unroll
        for (int i = 0; i < 4; ++i)
#pragma unroll
            for (int j = 0; j < 4; ++j)
                acc[i][j] = __builtin_amdgcn_mfma_f32_16x16x32_bf16(af[i], bfv[j], acc[i][j], 0, 0, 0);
        kt += 32;
        if (kt >= K) break;
        __syncthreads();
        stage(kt);
    }

    float* Cf = (float*)Cv + (long)blockIdx.z * sC;
    u16*   Ch = (u16*)Cv + (long)blockIdx.z * sC;

    float bcol[4];
    if constexpr (BIAS_MODE == 1) {
#pragma unroll
        for (int j = 0; j < 4; ++j) bcol[j] = bias[bn + wc * 64 + j * 16 + fr];
    }

#pragma unroll
    for (int i = 0; i < 4; ++i) {
        const int row0 = bm + wr * 64 + i * 16 + fq * 4;
#pragma unroll
        for (int r = 0; r < 4; ++r) {
            float badd = 0.f;
            if constexpr (BIAS_MODE == 2) badd = bias[row0 + r];
            const long base = (long)(row0 + r) * N + bn + wc * 64 + fr;
#pragma unroll
            for (int j = 0; j < 4; ++j) {
                float v = acc[i][j][r];
                if constexpr (BIAS_MODE == 1) v += bcol[j];
                if constexpr (BIAS_MODE == 2) v += badd;
                if constexpr (RELU) v = fmaxf(v, 0.f);
                if constexpr (OUT_BF16) Ch[base + j * 16] = f2bf(v);
                else                    Cf[base + j * 16] = v;
            }
        }
    }
}

// ------------------------------------------------------------------ SPLIT bf16 GEMM (NT)
// A ~ Ahi+Alo (lo plane at +loA elements), B likewise. 3 MFMA passes: hh+hl+lh.
// OUT_SPLIT: write hi plane + lo plane (at +loC); else fp32.
template<int BIAS_MODE, bool OUT_SPLIT>
__global__ __launch_bounds__(256)
void gemm_bf16s(const u16* __restrict__ A, const u16* __restrict__ B,
                const float* __restrict__ bias, void* __restrict__ Cv,
                int N, int K, long loA, long loB, long loC,
                long sA, long sB, long sC)
{
    __shared__ __bf16 Ah[128][32], Al[128][32], Bh[128][32], Bl[128][32];

    const u16* Ab = A + (long)blockIdx.z * sA;
    const u16* Bb = B + (long)blockIdx.z * sB;

    const int tid = threadIdx.x;
    const int lane = tid & 63;
    const int wid = tid >> 6;
    const int wr = wid >> 1, wc = wid & 1;
    const int fr = lane & 15, fq = lane >> 4;
    const int bm = blockIdx.y * 128;
    const int bn = blockIdx.x * 128;

    const int c0 = wid * 2;
    const int srow = lane >> 2;
    const int skof = (lane & 3) * 8;
    const u16* gA = Ab + (size_t)(bm + c0 * 16 + srow) * K + skof;
    const u16* gB = Bb + (size_t)(bn + c0 * 16 + srow) * K + skof;

    f32x4 acc[4][4];
#pragma unroll
    for (int i = 0; i < 4; ++i)
#pragma unroll
        for (int j = 0; j < 4; ++j) acc[i][j] = (f32x4){0.f, 0.f, 0.f, 0.f};

    auto stage = [&](int kt) {
        gload16(gA + kt,                        &Ah[c0 * 16][0]);
        gload16(gA + kt + (size_t)16 * K,       &Ah[c0 * 16 + 16][0]);
        gload16(gA + kt + loA,                  &Al[c0 * 16][0]);
        gload16(gA + kt + loA + (size_t)16 * K, &Al[c0 * 16 + 16][0]);
        gload16(gB + kt,                        &Bh[c0 * 16][0]);
        gload16(gB + kt + (size_t)16 * K,       &Bh[c0 * 16 + 16][0]);
        gload16(gB + kt + loB,                  &Bl[c0 * 16][0]);
        gload16(gB + kt + loB + (size_t)16 * K, &Bl[c0 * 16 + 16][0]);
    };

    stage(0);
    for (int kt = 0;;) {
        __syncthreads();
        bf16x8 ah[4], al[4], bh[4], bl[4];
#pragma unroll
        for (int i = 0; i < 4; ++i) {
            ah[i] = *reinterpret_cast<const bf16x8*>(&Ah[wr * 64 + i * 16 + fr][fq * 8]);
            al[i] = *reinterpret_cast<const bf16x8*>(&Al[wr * 64 + i * 16 + fr][fq * 8]);
        }
#pragma unroll
        for (int j = 0; j < 4; ++j) {
            bh[j] = *reinterpret_cast<const bf16x8*>(&Bh[wc * 64 + j * 16 + fr][fq * 8]);
            bl[j] = *reinterpret_cast<const bf16x8*>(&Bl[wc * 64 + j * 16 + fr][fq * 8]);
        }
#pragma unroll
        for (int i = 0; i < 4; ++i)
#pragma unroll
            for (int j = 0; j < 4; ++j) {
                acc[i][j] = __builtin_amdgcn_mfma_f32_16x16x32_bf16(ah[i], bh[j], acc[i][j], 0, 0, 0);
                acc[i][j] = __builtin_amdgcn_mfma_f32_16x16x32_bf16(ah[i], bl[j], acc[i][j], 0, 0, 0);
                acc[i][j] = __builtin_amdgcn_mfma_f32_16x16x32_bf16(al[i], bh[j], acc[i][j], 0, 0, 0);
            }
        kt += 32;
        if (kt >= K) break;
        __syncthreads();
        stage(kt);
    }

    float* Cf = (float*)Cv + (long)blockIdx.z * sC;
    u16*   Ch = (u16*)Cv + (long)blockIdx.z * sC;

    float bcol[4];
    if constexpr (BIAS_MODE == 1) {
#pragma unroll
        for (int j = 0; j < 4; ++j) bcol[j] = bias[bn + wc * 64 + j * 16 + fr];
    }

#pragma unroll
    for (int i = 0; i < 4; ++i) {
        const int row0 = bm + wr * 64 + i * 16 + fq * 4;
#pragma unroll
        for (int r = 0; r < 4; ++r) {
            float badd = 0.f;
            if constexpr (BIAS_MODE == 2) badd = bias[row0 + r];
            const long base = (long)(row0 + r) * N + bn + wc * 64 + fr;
#pragma unroll
            for (int j = 0; j < 4; ++j) {
                float v = acc[i][j][r];
                if constexpr (BIAS_MODE == 1) v += bcol[j];
                if constexpr (BIAS_MODE == 2) v += badd;
                if constexpr (OUT_SPLIT) {
                    const u16 hi = f2bf(v);
                    Ch[base + j * 16] = hi;
                    Ch[base + j * 16 + loC] = f2bf(v - bf2f(hi));
                } else {
                    Cf[base + j * 16] = v;
                }
            }
        }
    }
}

// ------------------------------------------------------------------ column softmax (axis=q)
__global__ __launch_bounds__(256)
void col_softmax(const float* __restrict__ logits, u16* __restrict__ attb)
{
    const int kx = threadIdx.x & 31;
    const int qy = threadIdx.x >> 5;
    const int k = blockIdx.x * 32 + kx;
    const float* __restrict__ base = logits + (long)blockIdx.y * kSS;
    u16* __restrict__ ob = attb + (long)blockIdx.y * kSS;

    __shared__ float redm[8][33];
    __shared__ float reds[8][33];

    const int q0 = k + ((qy - k) & 7);

    float m = -3.4e38f;
    for (int q = q0; q < kS; q += 8)
        m = fmaxf(m, base[(long)q * kS + k]);
    redm[qy][kx] = m;
    __syncthreads();
    if (qy == 0) {
#pragma unroll
        for (int r = 1; r < 8; ++r) m = fmaxf(m, redm[r][kx]);
        redm[0][kx] = m;
    }
    __syncthreads();
    m = redm[0][kx];

    float s = 0.f;
    for (int q = q0; q < kS; q += 8)
        s += __expf(base[(long)q * kS + k] - m);
    reds[qy][kx] = s;
    __syncthreads();
    if (qy == 0) {
#pragma unroll
        for (int r = 1; r < 8; ++r) s += reds[r][kx];
        reds[0][kx] = s;
    }
    __syncthreads();
    const float inv = 1.f / reds[0][kx];

    for (int q = qy; q < kS; q += 8) {
        const long idx = (long)q * kS + k;
        ob[idx] = (q >= k) ? f2bf(__expf(base[idx] - m) * inv) : (u16)0;
    }
}

// ------------------------------------------------------------------ add + LayerNorm (in-place residual, split bf16 out)
__global__ __launch_bounds__(256)
void add_ln(const float* __restrict__ X, float* __restrict__ R,
            const float* __restrict__ g, const float* __restrict__ beta,
            u16* __restrict__ Yh, u16* __restrict__ Yl)
{
    const long row = blockIdx.x;
    const int t = threadIdx.x;
    float4 v = reinterpret_cast<const float4*>(X + row * kD)[t];
    const float4 r4 = reinterpret_cast<const float4*>(R + row * kD)[t];
    v.x += r4.x; v.y += r4.y; v.z += r4.z; v.w += r4.w;

    float sum = v.x + v.y + v.z + v.w;
    float sq = v.x * v.x + v.y * v.y + v.z * v.z + v.w * v.w;
#pragma unroll
    for (int o = 32; o > 0; o >>= 1) {
        sum += __shfl_xor(sum, o);
        sq  += __shfl_xor(sq, o);
    }
    __shared__ float wsum[4], wsq[4];
    const int wave = t >> 6;
    if ((t & 63) == 0) { wsum[wave] = sum; wsq[wave] = sq; }
    __syncthreads();
    sum = wsum[0] + wsum[1] + wsum[2] + wsum[3];
    sq  = wsq[0] + wsq[1] + wsq[2] + wsq[3];
    const float mu = sum * (1.f / kD);
    const float var = sq * (1.f / kD) - mu * mu;
    const float rs = rsqrtf(var + LN_EPS);

    const float4 gv = reinterpret_cast<const float4*>(g)[t];
    const float4 bv = reinterpret_cast<const float4*>(beta)[t];
    float4 o;
    o.x = (v.x - mu) * rs * gv.x + bv.x;
    o.y = (v.y - mu) * rs * gv.y + bv.y;
    o.z = (v.z - mu) * rs * gv.z + bv.z;
    o.w = (v.w - mu) * rs * gv.w + bv.w;
    reinterpret_cast<float4*>(R + row * kD)[t] = o;
    u16x4 hi = { f2bf(o.x), f2bf(o.y), f2bf(o.z), f2bf(o.w) };
    u16x4 lo = { f2bf(o.x - bf2f(hi.x)), f2bf(o.y - bf2f(hi.y)),
                 f2bf(o.z - bf2f(hi.z)), f2bf(o.w - bf2f(hi.w)) };
    reinterpret_cast<u16x4*>(Yh + row * kD)[t] = hi;
    reinterpret_cast<u16x4*>(Yl + row * kD)[t] = lo;
}

} // namespace

// ------------------------------------------------------------------ launch
extern "C" void kernel_launch(void* const* d_in, const int* in_sizes, int n_in,
                              void* d_out, int out_size, void* d_ws, size_t ws_size,
                              hipStream_t stream)
{
    const int*   x   = (const int*)d_in[0];
    const float* emb = (const float*)d_in[1];
    const float* pos = (const float*)d_in[2];
    const float* k1w = (const float*)d_in[3];  const float* k1b = (const float*)d_in[4];
    const float* q1w = (const float*)d_in[5];  const float* q1b = (const float*)d_in[6];
    const float* v1w = (const float*)d_in[7];  const float* v1b = (const float*)d_in[8];
    const float* k2w = (const float*)d_in[9];  const float* k2b = (const float*)d_in[10];
    const float* q2w = (const float*)d_in[11]; const float* q2b = (const float*)d_in[12];
    const float* v2w = (const float*)d_in[13]; const float* v2b = (const float*)d_in[14];
    const float* lng = (const float*)d_in[15]; const float* lnb = (const float*)d_in[16];
    const float* ffw = (const float*)d_in[17]; const float* ffb = (const float*)d_in[18];
    const float* ow  = (const float*)d_in[19]; const float* ob  = (const float*)d_in[20];
    float* out = (float*)d_out;

    // ---- workspace layout (bytes), total 148,897,792 (< round-1's proven 150,994,944)
    char* wsb = (char*)d_ws;
    float* hR   = (float*)(wsb + 0);             // 16.78 MB
    u16*   hHi  = (u16*)  (wsb + 16777216);      // 8.39 MB
    u16*   hLo  = (u16*)  (wsb + 25165824);      // 8.39 MB  (= hHi + kBSD elements)
    u16*   kHi  = (u16*)  (wsb + 33554432);      // 8.39 MB  (later: ff1)
    u16*   kLo  = (u16*)  (wsb + 41943040);      // 8.39 MB  (later: ff2)
    u16*   wsm  = (u16*)  (wsb + 50331648);      // 11 x 2 MB weight planes
    u16*   qHi  = (u16*)  (wsb + 73400320);      // 8.39 MB  (attb reuses qHi..qLo)
    u16*   qLo  = (u16*)  (wsb + 81788928);      // 8.39 MB
    u16*   vtb  = (u16*)  (wsb + 90177536);      // 8.39 MB
    float* lg   = (float*)(wsb + 98566144);      // 33.55 MB
    float* ao   = (float*)(wsb + 132120576);     // 16.78 MB, ends 148,897,792
    u16*   attb = qHi;                           // 16.78 MB (q planes dead after QK^T)
    u16*   outwb= (u16*)  (wsb + 73400320);      // 65.54 MB over q/vt/lg/ao (dead at FF time)
    u16*   f1   = kHi;
    u16*   f2   = kLo;

    u16* wk1 = wsm;           u16* wq1 = wsm + 1 * kDD;  u16* wv1 = wsm + 2 * kDD;
    u16* wk2 = wsm + 3 * kDD; u16* wq2 = wsm + 4 * kDD;  u16* wv2 = wsm + 5 * kDD;
    u16* wff = wsm + 6 * kDD;
    const long wk1Lo = 7 * kDD, wq1Lo = 7 * kDD;   // plane 7 - plane 0, plane 8 - plane 1
    const long wk2Lo = 6 * kDD, wq2Lo = 6 * kDD;   // plane 9 - plane 3, plane 10 - plane 4

    const dim3 blk(256);

    W7 w7; w7.p[0]=k1w; w7.p[1]=q1w; w7.p[2]=v1w; w7.p[3]=k2w; w7.p[4]=q2w; w7.p[5]=v2w; w7.p[6]=ffw;
    hipLaunchKernelGGL(cvt7s, dim3((unsigned)(kDD / 1024), 7), blk, 0, stream, w7, wsm);
    hipLaunchKernelGGL(embed_k, dim3(kBS), blk, 0, stream, x, emb, pos, hR, hHi, hLo);

    auto attention = [&](const u16* wk_, long wkLo, const float* kbias,
                         const u16* wq_, long wqLo, const float* qbias,
                         const u16* wv_, const float* vbias) {
        // Q,K projections (split x split -> split out)
        hipLaunchKernelGGL((gemm_bf16s<1, true>), dim3(kD/128, kBS/128, 1), blk, 0, stream,
                           hHi, wq_, qbias, qHi, kD, kD, kBSD, wqLo, kBSD, 0L, 0L, 0L);
        hipLaunchKernelGGL((gemm_bf16s<1, true>), dim3(kD/128, kBS/128, 1), blk, 0, stream,
                           hHi, wk_, kbias, kHi, kD, kD, kBSD, wkLo, kBSD, 0L, 0L, 0L);
        // V^T (plain): vt[d,s] = Wv[d,:] . h[s,:], row bias, batched
        hipLaunchKernelGGL((gemm_bf16<2, false, true>), dim3(kS/128, kD/128, kB), blk, 0, stream,
                           wv_, hHi, vbias, vtb, kS, kD, 0L, kSD, kSD);
        // QK^T (split x split -> fp32 logits), batched
        hipLaunchKernelGGL((gemm_bf16s<0, false>), dim3(kS/128, kS/128, kB), blk, 0, stream,
                           qHi, kHi, (const float*)nullptr, lg, kS, kD, kBSD, kBSD, 0L,
                           kSD, kSD, kSS);
        // column softmax -> bf16 att (attb overwrites dead q planes)
        hipLaunchKernelGGL(col_softmax, dim3(kS/32, kB), blk, 0, stream, lg, attb);
        // PV (plain): ao[q,d] = att[q,:] . vt[d,:], batched
        hipLaunchKernelGGL((gemm_bf16<0, false, false>), dim3(kD/128, kS/128, kB), blk, 0, stream,
                           attb, vtb, (const float*)nullptr, ao, kD, kS, kSS, kSD, kSD);
    };

    // layer 1
    attention(wk1, wk1Lo, k1b, wq1, wq1Lo, q1b, wv1, v1b);
    hipLaunchKernelGGL(add_ln, dim3(kBS), blk, 0, stream, ao, hR, lng, lnb, hHi, hLo);
    // layer 2
    attention(wk2, wk2Lo, k2b, wq2, wq2Lo, q2b, wv2, v2b);
    hipLaunchKernelGGL(add_ln, dim3(kBS), blk, 0, stream, ao, hR, lng, lnb, hHi, hLo);

    // vocab weights -> bf16 (over dead q/vt/lg/ao region)
    hipLaunchKernelGGL(cvt_big, dim3(4096), blk, 0, stream, ow, outwb, (long)kV * kD / 4);

    // FF: same linear twice (relu between), plain bf16
    hipLaunchKernelGGL((gemm_bf16<1, true,  true>), dim3(kD/128, kBS/128, 1), blk, 0, stream,
                       hHi, wff, ffb, f1, kD, kD, 0L, 0L, 0L);
    hipLaunchKernelGGL((gemm_bf16<1, false, true>), dim3(kD/128, kBS/128, 1), blk, 0, stream,
                       f1, wff, ffb, f2, kD, kD, 0L, 0L, 0L);

    // vocab projection -> d_out (fp32)
    hipLaunchKernelGGL((gemm_bf16<1, false, false>), dim3(kV/128, kBS/128, 1), blk, 0, stream,
                       f2, outwb, ob, out, kV, kD, 0L, 0L, 0L);
}